// Round 5
// baseline (265.967 us; speedup 1.0000x reference)
//
#include <hip/hip_runtime.h>
#include <stdint.h>

#define NB 4
#define NPTS 4096
#define MPTS 16384
#define CIN 256
#define CH0 512
#define CH1 512
#define CH2 256
#define ROWS (NB * MPTS)          // 65536
#define POS_OUT_OFF (ROWS * CH2)               // 16777216
#define BATCH_OUT_OFF (POS_OUT_OFF + ROWS * 3) // 16973824
#define CELL_CAP 40               // lambda=8/cell
#define QCAP 96                   // lambda=32/cell

using u16 = unsigned short;
using u32 = unsigned int;
using u64 = unsigned long long;

typedef __bf16 bf16x8 __attribute__((ext_vector_type(8)));
typedef float f32x4 __attribute__((ext_vector_type(4)));

__device__ __forceinline__ u16 f2bf(float f) {
  u32 u = __builtin_bit_cast(u32, f);
  u32 r = u + 0x7fffu + ((u >> 16) & 1u);   // round-to-nearest-even
  return (u16)(r >> 16);
}

__device__ __forceinline__ float bf2f(u16 h) {
  return __builtin_bit_cast(float, (u32)h << 16);
}

__device__ __forceinline__ u32 flipf(float f) {
  u32 u = __builtin_bit_cast(u32, f);
  return u ^ ((u32)((int)u >> 31) | 0x80000000u);
}
__device__ __forceinline__ float unflipf(u32 f) {
  u32 m = (~(u32)((int)f >> 31)) | 0x80000000u;
  return __builtin_bit_cast(float, f ^ m);
}

__device__ __forceinline__ void ins3(u64 v, u64& k0, u64& k1, u64& k2) {
  u64 a = k0 < v ? v : k0;
  k0 = k0 < v ? k0 : v;
  u64 bb = k1 < a ? a : k1;
  k1 = k1 < a ? k1 : a;
  k2 = k2 < bb ? k2 : bb;
}

__device__ __forceinline__ void merge3(u64 r0, u64 r1, u64 r2,
                                       u64& k0, u64& k1, u64& k2) {
  u64 t = k0 < r0 ? r0 : k0;
  k0 = k0 < r0 ? k0 : r0;
  u64 u = k1 < r1 ? k1 : r1;
  u64 mtu = t < u ? u : t;
  k1 = t < u ? t : u;
  u64 v = k2 < r2 ? k2 : r2;
  k2 = mtu < v ? mtu : v;
}

__device__ __forceinline__ u64 shfl_xor_u64_w8(u64 v, int mask) {
  u32 lo = (u32)v, hi = (u32)(v >> 32);
  lo = (u32)__shfl_xor((int)lo, mask, 8);
  hi = (u32)__shfl_xor((int)hi, mask, 8);
  return ((u64)hi << 32) | lo;
}

// ---------------------------------------------------------------- prep + tail
__global__ __launch_bounds__(256) void preptail_kernel(
    const float* __restrict__ W1, const float* __restrict__ W2,
    u16* __restrict__ W1s, u16* __restrict__ W2s,
    const float* __restrict__ pos_skip, const int* __restrict__ batch_skip,
    float* __restrict__ out) {
  const int bid = blockIdx.x;
  if (bid < 192) {
    const int t = bid * 256 + threadIdx.x;   // 49152 threads
    if (t < 32768) {
      const int l = t & 63, ni = (t >> 6) & 3, wd = (t >> 8) & 7, kt = t >> 11;
      const int fr = l & 15, g = l >> 4;
      const int n = wd * 64 + ni * 16 + fr;
      u16 o[8];
#pragma unroll
      for (int j = 0; j < 8; ++j)
        o[j] = f2bf(W1[(kt * 32 + g * 8 + j) * CH1 + n]);
      *(uint4*)(W1s + (size_t)t * 8) = *(const uint4*)o;
    } else {
      const int c = t - 32768;                      // 0..16383
      const int l = c & 63, ni = (c >> 6) & 1, wd = (c >> 7) & 7, kt = c >> 10;
      const int fr = l & 15, g = l >> 4;
      const int n = wd * 32 + ni * 16 + fr;
      u16 o[8];
#pragma unroll
      for (int j = 0; j < 8; ++j)
        o[j] = f2bf(W2[(kt * 32 + g * 8 + j) * CH2 + n]);
      *(uint4*)(W2s + (size_t)c * 8) = *(const uint4*)o;
    }
  } else {
    const int t = (bid - 192) * 256 + threadIdx.x;   // 262144 total
    if (t < ROWS * 3) {
      out[POS_OUT_OFF + t] = pos_skip[t];
    } else {
      int u = t - ROWS * 3;
      out[BATCH_OUT_OFF + u] = (float)batch_skip[u];
    }
  }
}

// ---------------------------------------------------------------- build + qbin
__global__ __launch_bounds__(256) void bin_kernel(
    const float* __restrict__ pos, float4* __restrict__ pts4,
    u32* __restrict__ cellCnt, int* __restrict__ cellIdx,
    const float* __restrict__ pos_skip, u32* __restrict__ qCnt,
    int* __restrict__ qIdx) {
#pragma clang fp contract(off)
  if (blockIdx.x < 64) {
    const int i = blockIdx.x * 256 + threadIdx.x;   // 16384
    const float x = pos[i * 3 + 0], y = pos[i * 3 + 1], z = pos[i * 3 + 2];
    pts4[i] = make_float4(x, y, z, (x * x + y * y) + z * z);
    const int b = i >> 12;
    int cx = (int)(x * 8.0f); cx = cx < 0 ? 0 : (cx > 7 ? 7 : cx);
    int cy = (int)(y * 8.0f); cy = cy < 0 ? 0 : (cy > 7 ? 7 : cy);
    int cz = (int)(z * 8.0f); cz = cz < 0 ? 0 : (cz > 7 ? 7 : cz);
    const int c = b * 512 + cz * 64 + cy * 8 + cx;
    const u32 slot = atomicAdd(&cellCnt[c], 1u);
    if (slot < CELL_CAP) cellIdx[c * CELL_CAP + slot] = i;
  } else {
    const int q = (blockIdx.x - 64) * 256 + threadIdx.x;   // 65536
    const int b = q >> 14;
    const float qx = pos_skip[q * 3 + 0];
    const float qy = pos_skip[q * 3 + 1];
    const float qz = pos_skip[q * 3 + 2];
    int cx = (int)(qx * 8.0f); cx = cx < 0 ? 0 : (cx > 7 ? 7 : cx);
    int cy = (int)(qy * 8.0f); cy = cy < 0 ? 0 : (cy > 7 ? 7 : cy);
    int cz = (int)(qz * 8.0f); cz = cz < 0 ? 0 : (cz > 7 ? 7 : cz);
    const int c = b * 512 + cz * 64 + cy * 8 + cx;
    const u32 slot = atomicAdd(&qCnt[c], 1u);
    if (slot < QCAP) qIdx[c * QCAP + slot] = q;
  }
}

// ---------------------------------------------------------------- KNN (k=3)
// blocks 0..2047: KNN.  blocks 2048..2051: qPerm build.
__global__ __launch_bounds__(256) void knn_kernel(
    const float4* __restrict__ pts4, const u32* __restrict__ cellCnt,
    const int* __restrict__ cellIdx, const u32* __restrict__ qCnt,
    const int* __restrict__ qIdx, const float* __restrict__ pos_skip,
    int* __restrict__ idx_out, float* __restrict__ w_out,
    int* __restrict__ qPerm) {
#pragma clang fp contract(off)
  __shared__ float4 scand[27 * CELL_CAP];
  __shared__ int    scgi[27 * CELL_CAP];
  __shared__ u32    scnt[27];
  __shared__ int    sbase[27];
  __shared__ u32    nCand;
  __shared__ u32    ssc[256];
  const int tid = threadIdx.x;

  if (blockIdx.x >= 2048) {
    // ---- qPerm: one block per batch; 256 threads scan 512 cell counts.
    const int b = blockIdx.x - 2048;
    u32 c0 = qCnt[b * 512 + 2 * tid];     c0 = c0 > QCAP ? QCAP : c0;
    u32 c1 = qCnt[b * 512 + 2 * tid + 1]; c1 = c1 > QCAP ? QCAP : c1;
    const u32 ps = c0 + c1;
    u32 run = ps;
    ssc[tid] = run;
    for (int off = 1; off < 256; off <<= 1) {
      __syncthreads();
      u32 t = (tid >= off) ? ssc[tid - off] : 0u;
      __syncthreads();
      run += t;
      ssc[tid] = run;
    }
    const u32 excl = run - ps;
    const int base = b * MPTS + (int)excl;
    const int s0 = (b * 512 + 2 * tid) * QCAP;
    const int s1 = (b * 512 + 2 * tid + 1) * QCAP;
    for (u32 j = 0; j < c0; ++j) qPerm[base + j] = qIdx[s0 + j];
    for (u32 j = 0; j < c1; ++j) qPerm[base + c0 + j] = qIdx[s1 + j];
    return;
  }

  const int b = blockIdx.x >> 9;
  const int cell = blockIdx.x & 511;
  const int cz = cell >> 6, cy = (cell >> 3) & 7, cx = cell & 7;
  const int x0 = cx > 0 ? cx - 1 : 0, x1 = cx < 7 ? cx + 1 : 7;
  const int y0 = cy > 0 ? cy - 1 : 0, y1 = cy < 7 ? cy + 1 : 7;
  const int z0 = cz > 0 ? cz - 1 : 0, z1 = cz < 7 ? cz + 1 : 7;
  const int nx = x1 - x0 + 1, ny = y1 - y0 + 1, nz = z1 - z0 + 1;
  const int ncells = nx * ny * nz;
  if (tid == 0) nCand = 0;
  if (tid < ncells) {
    const int lz = tid / (nx * ny);
    const int rem = tid - lz * nx * ny;
    const int ly = rem / nx;
    const int lx = rem - ly * nx;
    const int cg = b * 512 + (z0 + lz) * 64 + (y0 + ly) * 8 + (x0 + lx);
    u32 cnt = cellCnt[cg];
    scnt[tid] = cnt > CELL_CAP ? CELL_CAP : cnt;
    sbase[tid] = cg * CELL_CAP;
  }
  __syncthreads();
  const int slots = ncells * CELL_CAP;
  for (int s = tid; s < slots; s += 256) {
    const int ci = s / CELL_CAP;
    const int sl = s - ci * CELL_CAP;
    if ((u32)sl < scnt[ci]) {
      const int gi = cellIdx[sbase[ci] + sl];
      const float4 p = pts4[gi];
      const u32 d = atomicAdd(&nCand, 1u);
      scand[d] = p;
      scgi[d] = gi;
    }
  }
  __syncthreads();
  const int nC = (int)nCand;
  u32 nq = qCnt[b * 512 + cell];
  if (nq > QCAP) nq = QCAP;
  const int qbase = (b * 512 + cell) * QCAP;
  const int g = tid >> 3;
  const int sub = tid & 7;

  for (int r0q = 0; r0q < (int)nq; r0q += 32) {
    const int qslot = r0q + g;
    if (qslot < (int)nq) {
      const int q = qIdx[qbase + qslot];
      const float qx = pos_skip[q * 3 + 0];
      const float qy = pos_skip[q * 3 + 1];
      const float qz = pos_skip[q * 3 + 2];
      const float q2 = (qx * qx + qy * qy) + qz * qz;
      u64 k0 = ~0ull, k1 = ~0ull, k2 = ~0ull;
      for (int s = sub; s < nC; s += 8) {
        const float4 p = scand[s];
        const float dot = fmaf(qz, p.z, fmaf(qy, p.y, qx * p.x));
        const float tv = (q2 - 2.0f * dot) + p.w;
        const u64 key = ((u64)flipf(tv) << 32) | (u32)scgi[s];
        ins3(key, k0, k1, k2);
      }
#pragma unroll
      for (int mask = 1; mask < 8; mask <<= 1) {
        const u64 r0 = shfl_xor_u64_w8(k0, mask);
        const u64 r1 = shfl_xor_u64_w8(k1, mask);
        const u64 r2 = shfl_xor_u64_w8(k2, mask);
        merge3(r0, r1, r2, k0, k1, k2);
      }
      float m2tv = unflipf((u32)(k2 >> 32));
      if (!(m2tv <= 0.015625f - 1e-5f)) {
        k0 = k1 = k2 = ~0ull;
        const int ex0 = cx > 1 ? cx - 2 : 0, ex1 = cx < 6 ? cx + 2 : 7;
        const int ey0 = cy > 1 ? cy - 2 : 0, ey1 = cy < 6 ? cy + 2 : 7;
        const int ez0 = cz > 1 ? cz - 2 : 0, ez1 = cz < 6 ? cz + 2 : 7;
        for (int zz = ez0; zz <= ez1; ++zz)
          for (int yy = ey0; yy <= ey1; ++yy)
            for (int xx = ex0; xx <= ex1; ++xx) {
              const int cg = b * 512 + zz * 64 + yy * 8 + xx;
              u32 cnt = cellCnt[cg];
              if (cnt > CELL_CAP) cnt = CELL_CAP;
              const int cb = cg * CELL_CAP;
              for (int s = sub; s < (int)cnt; s += 8) {
                const int gi = cellIdx[cb + s];
                const float4 p = pts4[gi];
                const float dot = fmaf(qz, p.z, fmaf(qy, p.y, qx * p.x));
                const float tv = (q2 - 2.0f * dot) + p.w;
                ins3(((u64)flipf(tv) << 32) | (u32)gi, k0, k1, k2);
              }
            }
#pragma unroll
        for (int mask = 1; mask < 8; mask <<= 1) {
          const u64 r0 = shfl_xor_u64_w8(k0, mask);
          const u64 r1 = shfl_xor_u64_w8(k1, mask);
          const u64 r2 = shfl_xor_u64_w8(k2, mask);
          merge3(r0, r1, r2, k0, k1, k2);
        }
        m2tv = unflipf((u32)(k2 >> 32));
        if (!(m2tv <= 0.0625f - 1e-5f)) {
          k0 = k1 = k2 = ~0ull;
          const int base = b * NPTS;
          for (int i = sub; i < NPTS; i += 8) {
            const int gi = base + i;
            const float4 p = pts4[gi];
            const float dot = fmaf(qz, p.z, fmaf(qy, p.y, qx * p.x));
            const float tv = (q2 - 2.0f * dot) + p.w;
            ins3(((u64)flipf(tv) << 32) | (u32)gi, k0, k1, k2);
          }
#pragma unroll
          for (int mask = 1; mask < 8; mask <<= 1) {
            const u64 r0 = shfl_xor_u64_w8(k0, mask);
            const u64 r1 = shfl_xor_u64_w8(k1, mask);
            const u64 r2 = shfl_xor_u64_w8(k2, mask);
            merge3(r0, r1, r2, k0, k1, k2);
          }
        }
      }
      if (sub == 0) {
        const float t0 = unflipf((u32)(k0 >> 32));
        const float t1 = unflipf((u32)(k1 >> 32));
        const float t2 = unflipf((u32)(k2 >> 32));
        const float w0 = 1.0f / fmaxf(t0, 1e-16f);
        const float w1 = 1.0f / fmaxf(t1, 1e-16f);
        const float w2 = 1.0f / fmaxf(t2, 1e-16f);
        const float wsum = (w0 + w1) + w2;
        const float inv = 1.0f / wsum;
        idx_out[q * 3 + 0] = (int)(u32)k0;
        idx_out[q * 3 + 1] = (int)(u32)k1;
        idx_out[q * 3 + 2] = (int)(u32)k2;
        w_out[q * 3 + 0] = w0 * inv;
        w_out[q * 3 + 1] = w1 * inv;
        w_out[q * 3 + 2] = w2 * inv;
      }
    }
  }
}

// ---------------------------------------------------------------- fused MLP
// R11: TA-transaction reduction. A-build in 2 sub-passes of 32 rows:
//  (1) hash-dedup the 96 (row,k) neighbor refs -> U<=96 uniques (hard bound),
//  (2) load unique x rows ONCE, fully coalesced (16 lines/instr vs 64 for
//      the old per-row gathers), into Xs[96][264] bf16 (padded stride),
//  (3) x_skip rows cooperatively loaded per-row coalesced straight to Abuf,
//  (4) interp combines from LDS.
// Phases 1/2, relu, epilogue identical to the measured-best R3 code.
// LDS ~119 KB -> 1 block/CU (traded for ~4x fewer A-build L1 lookups).
// Granule map p(vg,row) = (vg&32)|((vg&3)<<3)|(((vg>>2)&7)^(row&7)).
__global__ __launch_bounds__(512) void fused_mlp_kernel(
    const float* __restrict__ x, const int* __restrict__ idx,
    const float* __restrict__ w, const float* __restrict__ x_skip,
    const u16* __restrict__ W1s, const float* __restrict__ b1,
    const u16* __restrict__ W2s, const float* __restrict__ b2,
    const int* __restrict__ qPerm, float* __restrict__ out) {
  __shared__ __align__(16) u16 Abuf[64 * 512];   // 64 KB
  __shared__ __align__(16) u16 Xs[96 * 264];     // 49.5 KB (stride 264: +4 banks/row)
  __shared__ int   sPerm[64];
  __shared__ float sWt[96];
  __shared__ int   sSlot[96];
  __shared__ int   hKey[128];
  __shared__ int   hVal[128];
  __shared__ int   uList[96];
  __shared__ u32   uCnt;
  const int tid = threadIdx.x;
  const int m0 = blockIdx.x * 64;

  if (tid < 64) sPerm[tid] = qPerm[m0 + tid];

  // ---- A-build: 2 sub-passes x 32 rows
  for (int p = 0; p < 2; ++p) {
    if (tid < 128) hKey[tid] = -1;
    if (tid == 0) uCnt = 0;
    __syncthreads();                       // sPerm (p=0) / prev pass done; resets visible
    int myH = 0;
    if (tid < 96) {
      const int r = tid / 3, k = tid - r * 3;
      const int q = sPerm[p * 32 + r];
      const int key = idx[q * 3 + k];
      sWt[tid] = w[q * 3 + k];
      u32 h = (((u32)key * 2654435761u) >> 25) & 127u;
      for (;;) {
        const int prev = atomicCAS(&hKey[h], -1, key);
        if (prev == -1) {
          const int s = (int)atomicAdd(&uCnt, 1u);
          hVal[h] = s;
          uList[s] = key;
          myH = (int)h;
          break;
        }
        if (prev == key) { myH = (int)h; break; }
        h = (h + 1) & 127u;
      }
    }
    __syncthreads();                       // inserts, hVal, uList, uCnt complete
    const int U = (int)uCnt;
    if (tid < 96) sSlot[tid] = hVal[myH];
    if (tid < 256) {
      // unique x rows -> Xs, coalesced (wave = one full 1 KB row)
      for (int j = tid; j < U * 64; j += 256) {
        const int u = j >> 6, seg = j & 63;
        const float4 v = ((const float4*)x)[(size_t)uList[u] * 64 + seg];
        u16 o[4] = {f2bf(v.x), f2bf(v.y), f2bf(v.z), f2bf(v.w)};
        *(uint2*)&Xs[u * 264 + seg * 4] = *(const uint2*)o;
      }
    } else {
      // x_skip rows -> Abuf skip half, coalesced per row
      const int t2 = tid - 256;
      for (int j = t2; j < 32 * 64; j += 256) {
        const int r = j >> 6, seg = j & 63;
        const int row = p * 32 + r;
        const float4 v = ((const float4*)x_skip)[(size_t)sPerm[row] * 64 + seg];
        u16 o[4] = {f2bf(v.x), f2bf(v.y), f2bf(v.z), f2bf(v.w)};
        const int s5 = seg >> 1;           // vg - 32
        const int c = s5 & 3, ss = s5 >> 2;
        const int pp = 32 | (c << 3) | ((ss ^ (row & 7)) & 7);
        *(uint2*)&Abuf[row * 512 + pp * 8 + (seg & 1) * 4] = *(const uint2*)o;
      }
    }
    __syncthreads();                       // Xs + sSlot ready
    // interp: 32 rows x 8 col-slices from LDS
    if (tid < 256) {
      const int r = tid >> 3, sub = tid & 7;
      const int row = p * 32 + r;
      const int e = r * 3;
      const int s0 = sSlot[e], s1 = sSlot[e + 1], s2 = sSlot[e + 2];
      const float w0 = sWt[e], w1 = sWt[e + 1], w2 = sWt[e + 2];
      const u16* x0 = &Xs[s0 * 264 + sub * 32];
      const u16* x1 = &Xs[s1 * 264 + sub * 32];
      const u16* x2 = &Xs[s2 * 264 + sub * 32];
      const int rx = row & 7;
      u16* rowp = Abuf + row * 512;
#pragma unroll
      for (int c = 0; c < 4; ++c) {
        const uint4 v0 = *(const uint4*)(x0 + c * 8);
        const uint4 v1 = *(const uint4*)(x1 + c * 8);
        const uint4 v2 = *(const uint4*)(x2 + c * 8);
        const u32 a0[4] = {v0.x, v0.y, v0.z, v0.w};
        const u32 a1[4] = {v1.x, v1.y, v1.z, v1.w};
        const u32 a2[4] = {v2.x, v2.y, v2.z, v2.w};
        u16 o[8];
#pragma unroll
        for (int jj = 0; jj < 4; ++jj) {
          const float lo = fmaf(w0, __builtin_bit_cast(float, a0[jj] << 16),
                          fmaf(w1, __builtin_bit_cast(float, a1[jj] << 16),
                          w2 * __builtin_bit_cast(float, a2[jj] << 16)));
          const float hi = fmaf(w0, __builtin_bit_cast(float, a0[jj] & 0xffff0000u),
                          fmaf(w1, __builtin_bit_cast(float, a1[jj] & 0xffff0000u),
                          w2 * __builtin_bit_cast(float, a2[jj] & 0xffff0000u)));
          o[jj * 2]     = f2bf(lo);
          o[jj * 2 + 1] = f2bf(hi);
        }
        const int pp = (c << 3) | ((sub ^ rx) & 7);
        *(uint4*)(rowp + pp * 8) = *(const uint4*)o;
      }
    }
    __syncthreads();                       // sub-pass complete
  }

  const int wid = tid >> 6;
  const int lane = tid & 63;
  const int fr = lane & 15;
  const int g = lane >> 4;
  const int frx = fr & 7;

  // ---- phase 1: H[64][512] = A[64][512] @ W1 (wave: m64 x n64)
  f32x4 acc[4][4];
#pragma unroll
  for (int mi = 0; mi < 4; mi++)
#pragma unroll
    for (int ni = 0; ni < 4; ni++) acc[mi][ni] = (f32x4){0.f, 0.f, 0.f, 0.f};

  {
    const u16* B1 = W1s + wid * 2048 + lane * 8;   // + kt*16384 + ni*512
    bf16x8 bf[2][4];
#pragma unroll
    for (int ni = 0; ni < 4; ni++)
      bf[0][ni] = *(const bf16x8*)(B1 + ni * 512);
    for (int kt = 0; kt < 16; ++kt) {
      const int cur = kt & 1;
      if (kt < 15) {
        const u16* nb = B1 + (kt + 1) * 16384;
#pragma unroll
        for (int ni = 0; ni < 4; ni++)
          bf[cur ^ 1][ni] = *(const bf16x8*)(nb + ni * 512);
      }
      bf16x8 af[4];
#pragma unroll
      for (int mi = 0; mi < 4; mi++)
        af[mi] = *(const bf16x8*)&Abuf[(mi * 16 + fr) * 512 +
            ((((kt >> 3) << 5) | (g << 3) | ((kt & 7) ^ frx)) * 8)];
#pragma unroll
      for (int mi = 0; mi < 4; mi++)
#pragma unroll
        for (int ni = 0; ni < 4; ni++)
          acc[mi][ni] = __builtin_amdgcn_mfma_f32_16x16x32_bf16(
              af[mi], bf[cur][ni], acc[mi][ni], 0, 0, 0);
    }
  }
  __syncthreads();                 // all Abuf reads complete

  // ---- relu + bias -> bf16 back into Abuf (as H, same swizzle map)
  {
    const int wn = wid * 64;
#pragma unroll
    for (int ni = 0; ni < 4; ni++) {
      const int n = wn + ni * 16 + fr;
      const float bb = b1[n];
      const int vg = n >> 3;
      const int nlow = n & 7;
      const int pb = (vg & 32) | ((vg & 3) << 3) | ((vg >> 2) & 7);
#pragma unroll
      for (int mi = 0; mi < 4; mi++) {
#pragma unroll
        for (int r = 0; r < 4; r++) {
          const int m = mi * 16 + g * 4 + r;
          const float v = fmaxf(acc[mi][ni][r] + bb, 0.f);
          Abuf[m * 512 + (pb ^ (m & 7)) * 8 + nlow] = f2bf(v);
        }
      }
    }
  }
  __syncthreads();                 // H complete

  // ---- phase 2: C[64][256] = H[64][512] @ W2 (wave: m64 x n32)
  f32x4 acc2[4][2];
#pragma unroll
  for (int mi = 0; mi < 4; mi++)
#pragma unroll
    for (int ni = 0; ni < 2; ni++) acc2[mi][ni] = (f32x4){0.f, 0.f, 0.f, 0.f};

  {
    const u16* B2 = W2s + wid * 1024 + lane * 8;   // + kt*8192 + ni*512
    bf16x8 bf[2][2];
#pragma unroll
    for (int ni = 0; ni < 2; ni++)
      bf[0][ni] = *(const bf16x8*)(B2 + ni * 512);
    for (int kt = 0; kt < 16; ++kt) {
      const int cur = kt & 1;
      if (kt < 15) {
        const u16* nb = B2 + (kt + 1) * 8192;
#pragma unroll
        for (int ni = 0; ni < 2; ni++)
          bf[cur ^ 1][ni] = *(const bf16x8*)(nb + ni * 512);
      }
      bf16x8 af[4];
#pragma unroll
      for (int mi = 0; mi < 4; mi++)
        af[mi] = *(const bf16x8*)&Abuf[(mi * 16 + fr) * 512 +
            ((((kt >> 3) << 5) | (g << 3) | ((kt & 7) ^ frx)) * 8)];
#pragma unroll
      for (int mi = 0; mi < 4; mi++)
#pragma unroll
        for (int ni = 0; ni < 2; ni++)
          acc2[mi][ni] = __builtin_amdgcn_mfma_f32_16x16x32_bf16(
              af[mi], bf[cur][ni], acc2[mi][ni], 0, 0, 0);
    }
  }

  // ---- epilogue: relu + bias2 -> f32 out (rows via sPerm)
#pragma unroll
  for (int ni = 0; ni < 2; ni++) {
    const int col = wid * 32 + ni * 16 + fr;
    const float bb = b2[col];
#pragma unroll
    for (int mi = 0; mi < 4; mi++) {
#pragma unroll
      for (int r = 0; r < 4; r++) {
        const int rowg = sPerm[mi * 16 + g * 4 + r];
        out[(size_t)rowg * CH2 + col] = fmaxf(acc2[mi][ni][r] + bb, 0.f);
      }
    }
  }
}

// ---------------------------------------------------------------- launch
extern "C" void kernel_launch(void* const* d_in, const int* in_sizes, int n_in,
                              void* d_out, int out_size, void* d_ws, size_t ws_size,
                              hipStream_t stream) {
  const float* x        = (const float*)d_in[0];
  const float* pos      = (const float*)d_in[1];
  const float* x_skip   = (const float*)d_in[3];
  const float* pos_skip = (const float*)d_in[4];
  const int*   batch_sk = (const int*)d_in[5];
  const float* W1       = (const float*)d_in[6];
  const float* b1       = (const float*)d_in[7];
  const float* W2       = (const float*)d_in[8];
  const float* b2       = (const float*)d_in[9];
  float* out = (float*)d_out;

  char* ws = (char*)d_ws;
  u16*    W1s     = (u16*)(ws);                 // 524288 B
  u16*    W2s     = (u16*)(ws + 524288);        // 262144 B
  int*    idxb    = (int*)(ws + 786432);        // 786432 B
  float*  wb      = (float*)(ws + 1572864);     // 786432 B
  float4* pts4    = (float4*)(ws + 2359296);    // 262144 B
  u32*    cellCnt = (u32*)(ws + 2621440);       // 8192 B
  u32*    qCnt    = (u32*)(ws + 2629632);       // 8192 B
  int*    cellIdx = (int*)(ws + 2637824);       // 327680 B
  int*    qIdx    = (int*)(ws + 2965504);       // 786432 B
  int*    qPerm   = (int*)(ws + 3751936);       // 262144 B
  // total 4,014,080 B

  hipMemsetAsync(cellCnt, 0, 16384, stream);    // cellCnt + qCnt
  preptail_kernel<<<dim3(1216), dim3(256), 0, stream>>>(
      W1, W2, W1s, W2s, pos_skip, batch_sk, out);
  bin_kernel<<<dim3(320), dim3(256), 0, stream>>>(
      pos, pts4, cellCnt, cellIdx, pos_skip, qCnt, qIdx);
  knn_kernel<<<dim3(2052), dim3(256), 0, stream>>>(pts4, cellCnt, cellIdx,
                                                   qCnt, qIdx, pos_skip,
                                                   idxb, wb, qPerm);
  fused_mlp_kernel<<<dim3(1024), dim3(512), 0, stream>>>(
      x, idxb, wb, x_skip, W1s, b1, W2s, b2, qPerm, out);
}

// Round 6
// 264.562 us; speedup vs baseline: 1.0053x; 1.0053x over previous
//
#include <hip/hip_runtime.h>
#include <stdint.h>

#define NB 4
#define NPTS 4096
#define MPTS 16384
#define CIN 256
#define CH0 512
#define CH1 512
#define CH2 256
#define ROWS (NB * MPTS)          // 65536
#define POS_OUT_OFF (ROWS * CH2)               // 16777216
#define BATCH_OUT_OFF (POS_OUT_OFF + ROWS * 3) // 16973824
#define CELL_CAP 40               // lambda=8/cell
#define QCAP 96                   // lambda=32/cell

using u16 = unsigned short;
using u32 = unsigned int;
using u64 = unsigned long long;

typedef __bf16 bf16x8 __attribute__((ext_vector_type(8)));
typedef float f32x4 __attribute__((ext_vector_type(4)));

__device__ __forceinline__ u16 f2bf(float f) {
  u32 u = __builtin_bit_cast(u32, f);
  u32 r = u + 0x7fffu + ((u >> 16) & 1u);   // round-to-nearest-even
  return (u16)(r >> 16);
}

__device__ __forceinline__ u32 flipf(float f) {
  u32 u = __builtin_bit_cast(u32, f);
  return u ^ ((u32)((int)u >> 31) | 0x80000000u);
}
__device__ __forceinline__ float unflipf(u32 f) {
  u32 m = (~(u32)((int)f >> 31)) | 0x80000000u;
  return __builtin_bit_cast(float, f ^ m);
}

__device__ __forceinline__ void ins3(u64 v, u64& k0, u64& k1, u64& k2) {
  u64 a = k0 < v ? v : k0;
  k0 = k0 < v ? k0 : v;
  u64 bb = k1 < a ? a : k1;
  k1 = k1 < a ? k1 : a;
  k2 = k2 < bb ? k2 : bb;
}

__device__ __forceinline__ void merge3(u64 r0, u64 r1, u64 r2,
                                       u64& k0, u64& k1, u64& k2) {
  u64 t = k0 < r0 ? r0 : k0;
  k0 = k0 < r0 ? k0 : r0;
  u64 u = k1 < r1 ? k1 : r1;
  u64 mtu = t < u ? u : t;
  k1 = t < u ? t : u;
  u64 v = k2 < r2 ? k2 : r2;
  k2 = mtu < v ? mtu : v;
}

__device__ __forceinline__ u64 shfl_xor_u64_w8(u64 v, int mask) {
  u32 lo = (u32)v, hi = (u32)(v >> 32);
  lo = (u32)__shfl_xor((int)lo, mask, 8);
  hi = (u32)__shfl_xor((int)hi, mask, 8);
  return ((u64)hi << 32) | lo;
}

__device__ __forceinline__ u64 shfl_xor_u64_w64(u64 v, int mask) {
  u32 lo = (u32)v, hi = (u32)(v >> 32);
  lo = (u32)__shfl_xor((int)lo, mask, 64);
  hi = (u32)__shfl_xor((int)hi, mask, 64);
  return ((u64)hi << 32) | lo;
}

// ------------------------------------------------- prep + tail + build + qbin
// bid <192: W-pack; <1216: tail copy; <1280: cell build; <1536: query bin.
__global__ __launch_bounds__(256) void ptbin_kernel(
    const float* __restrict__ W1, const float* __restrict__ W2,
    u16* __restrict__ W1s, u16* __restrict__ W2s,
    const float* __restrict__ pos_skip, const int* __restrict__ batch_skip,
    float* __restrict__ out, const float* __restrict__ pos,
    float4* __restrict__ pts4, u32* __restrict__ cellCnt,
    int* __restrict__ cellIdx, u32* __restrict__ qCnt,
    int* __restrict__ qIdx) {
#pragma clang fp contract(off)
  const int bid = blockIdx.x;
  if (bid < 192) {
    const int t = bid * 256 + threadIdx.x;   // 49152 threads
    if (t < 32768) {
      const int l = t & 63, ni = (t >> 6) & 3, wd = (t >> 8) & 7, kt = t >> 11;
      const int fr = l & 15, g = l >> 4;
      const int n = wd * 64 + ni * 16 + fr;
      u16 o[8];
#pragma unroll
      for (int j = 0; j < 8; ++j)
        o[j] = f2bf(W1[(kt * 32 + g * 8 + j) * CH1 + n]);
      *(uint4*)(W1s + (size_t)t * 8) = *(const uint4*)o;
    } else {
      const int c = t - 32768;                      // 0..16383
      const int l = c & 63, ni = (c >> 6) & 1, wd = (c >> 7) & 7, kt = c >> 10;
      const int fr = l & 15, g = l >> 4;
      const int n = wd * 32 + ni * 16 + fr;
      u16 o[8];
#pragma unroll
      for (int j = 0; j < 8; ++j)
        o[j] = f2bf(W2[(kt * 32 + g * 8 + j) * CH2 + n]);
      *(uint4*)(W2s + (size_t)c * 8) = *(const uint4*)o;
    }
  } else if (bid < 1216) {
    const int t = (bid - 192) * 256 + threadIdx.x;   // 262144 total
    if (t < ROWS * 3) {
      out[POS_OUT_OFF + t] = pos_skip[t];
    } else {
      int u = t - ROWS * 3;
      out[BATCH_OUT_OFF + u] = (float)batch_skip[u];
    }
  } else if (bid < 1280) {
    const int i = (bid - 1216) * 256 + threadIdx.x;   // 16384
    const float x = pos[i * 3 + 0], y = pos[i * 3 + 1], z = pos[i * 3 + 2];
    pts4[i] = make_float4(x, y, z, (x * x + y * y) + z * z);
    const int b = i >> 12;
    int cx = (int)(x * 8.0f); cx = cx < 0 ? 0 : (cx > 7 ? 7 : cx);
    int cy = (int)(y * 8.0f); cy = cy < 0 ? 0 : (cy > 7 ? 7 : cy);
    int cz = (int)(z * 8.0f); cz = cz < 0 ? 0 : (cz > 7 ? 7 : cz);
    const int c = b * 512 + cz * 64 + cy * 8 + cx;
    const u32 slot = atomicAdd(&cellCnt[c], 1u);
    if (slot < CELL_CAP) cellIdx[c * CELL_CAP + slot] = i;
  } else {
    const int q = (bid - 1280) * 256 + threadIdx.x;   // 65536
    const int b = q >> 14;
    const float qx = pos_skip[q * 3 + 0];
    const float qy = pos_skip[q * 3 + 1];
    const float qz = pos_skip[q * 3 + 2];
    int cx = (int)(qx * 8.0f); cx = cx < 0 ? 0 : (cx > 7 ? 7 : cx);
    int cy = (int)(qy * 8.0f); cy = cy < 0 ? 0 : (cy > 7 ? 7 : cy);
    int cz = (int)(qz * 8.0f); cz = cz < 0 ? 0 : (cz > 7 ? 7 : cz);
    const int c = b * 512 + cz * 64 + cy * 8 + cx;
    const u32 slot = atomicAdd(&qCnt[c], 1u);
    if (slot < QCAP) qIdx[c * QCAP + slot] = q;
  }
}

// ---------------------------------------------------------------- KNN (k=3)
// Pass-1 only (staged 3x3x3 window). Failing query groups (d3 > cell width)
// are DEFERRED to fixup_kernel via a global overflow list instead of running
// the serial 5x5x5 global rescan inline (which stalled the whole wave on
// ~25K cycles of dependent loads). blocks 2048..2051: qPerm build.
__global__ __launch_bounds__(256) void knn_kernel(
    const float4* __restrict__ pts4, const u32* __restrict__ cellCnt,
    const int* __restrict__ cellIdx, const u32* __restrict__ qCnt,
    const int* __restrict__ qIdx, const float* __restrict__ pos_skip,
    int* __restrict__ idx_out, float* __restrict__ w_out,
    int* __restrict__ qPerm, u32* __restrict__ ovCnt,
    int* __restrict__ ovList) {
#pragma clang fp contract(off)
  __shared__ float4 scand[27 * CELL_CAP];
  __shared__ int    scgi[27 * CELL_CAP];
  __shared__ u32    scnt[27];
  __shared__ int    sbase[27];
  __shared__ u32    nCand;
  __shared__ u32    ssc[256];
  const int tid = threadIdx.x;

  if (blockIdx.x >= 2048) {
    // ---- qPerm: one block per batch; 256 threads scan 512 cell counts.
    const int b = blockIdx.x - 2048;
    u32 c0 = qCnt[b * 512 + 2 * tid];     c0 = c0 > QCAP ? QCAP : c0;
    u32 c1 = qCnt[b * 512 + 2 * tid + 1]; c1 = c1 > QCAP ? QCAP : c1;
    const u32 ps = c0 + c1;
    u32 run = ps;
    ssc[tid] = run;
    for (int off = 1; off < 256; off <<= 1) {
      __syncthreads();
      u32 t = (tid >= off) ? ssc[tid - off] : 0u;
      __syncthreads();
      run += t;
      ssc[tid] = run;
    }
    const u32 excl = run - ps;
    const int base = b * MPTS + (int)excl;
    const int s0 = (b * 512 + 2 * tid) * QCAP;
    const int s1 = (b * 512 + 2 * tid + 1) * QCAP;
    for (u32 j = 0; j < c0; ++j) qPerm[base + j] = qIdx[s0 + j];
    for (u32 j = 0; j < c1; ++j) qPerm[base + c0 + j] = qIdx[s1 + j];
    return;
  }

  const int b = blockIdx.x >> 9;
  const int cell = blockIdx.x & 511;
  const int cz = cell >> 6, cy = (cell >> 3) & 7, cx = cell & 7;
  const int x0 = cx > 0 ? cx - 1 : 0, x1 = cx < 7 ? cx + 1 : 7;
  const int y0 = cy > 0 ? cy - 1 : 0, y1 = cy < 7 ? cy + 1 : 7;
  const int z0 = cz > 0 ? cz - 1 : 0, z1 = cz < 7 ? cz + 1 : 7;
  const int nx = x1 - x0 + 1, ny = y1 - y0 + 1, nz = z1 - z0 + 1;
  const int ncells = nx * ny * nz;
  if (tid == 0) nCand = 0;
  if (tid < ncells) {
    const int lz = tid / (nx * ny);
    const int rem = tid - lz * nx * ny;
    const int ly = rem / nx;
    const int lx = rem - ly * nx;
    const int cg = b * 512 + (z0 + lz) * 64 + (y0 + ly) * 8 + (x0 + lx);
    u32 cnt = cellCnt[cg];
    scnt[tid] = cnt > CELL_CAP ? CELL_CAP : cnt;
    sbase[tid] = cg * CELL_CAP;
  }
  __syncthreads();
  const int slots = ncells * CELL_CAP;
  for (int s = tid; s < slots; s += 256) {
    const int ci = s / CELL_CAP;
    const int sl = s - ci * CELL_CAP;
    if ((u32)sl < scnt[ci]) {
      const int gi = cellIdx[sbase[ci] + sl];
      const float4 p = pts4[gi];
      const u32 d = atomicAdd(&nCand, 1u);
      scand[d] = p;
      scgi[d] = gi;
    }
  }
  __syncthreads();
  const int nC = (int)nCand;
  u32 nq = qCnt[b * 512 + cell];
  if (nq > QCAP) nq = QCAP;
  const int qbase = (b * 512 + cell) * QCAP;
  const int g = tid >> 3;
  const int sub = tid & 7;

  for (int r0q = 0; r0q < (int)nq; r0q += 32) {
    const int qslot = r0q + g;
    if (qslot < (int)nq) {
      const int q = qIdx[qbase + qslot];
      const float qx = pos_skip[q * 3 + 0];
      const float qy = pos_skip[q * 3 + 1];
      const float qz = pos_skip[q * 3 + 2];
      const float q2 = (qx * qx + qy * qy) + qz * qz;
      u64 k0 = ~0ull, k1 = ~0ull, k2 = ~0ull;
      for (int s = sub; s < nC; s += 8) {
        const float4 p = scand[s];
        const float dot = fmaf(qz, p.z, fmaf(qy, p.y, qx * p.x));
        const float tv = (q2 - 2.0f * dot) + p.w;
        const u64 key = ((u64)flipf(tv) << 32) | (u32)scgi[s];
        ins3(key, k0, k1, k2);
      }
#pragma unroll
      for (int mask = 1; mask < 8; mask <<= 1) {
        const u64 r0 = shfl_xor_u64_w8(k0, mask);
        const u64 r1 = shfl_xor_u64_w8(k1, mask);
        const u64 r2 = shfl_xor_u64_w8(k2, mask);
        merge3(r0, r1, r2, k0, k1, k2);
      }
      const float m2tv = unflipf((u32)(k2 >> 32));
      if (m2tv <= 0.015625f - 1e-5f) {
        if (sub == 0) {
          const float t0 = unflipf((u32)(k0 >> 32));
          const float t1 = unflipf((u32)(k1 >> 32));
          const float t2 = unflipf((u32)(k2 >> 32));
          const float w0 = 1.0f / fmaxf(t0, 1e-16f);
          const float w1 = 1.0f / fmaxf(t1, 1e-16f);
          const float w2 = 1.0f / fmaxf(t2, 1e-16f);
          const float wsum = (w0 + w1) + w2;
          const float inv = 1.0f / wsum;
          idx_out[q * 3 + 0] = (int)(u32)k0;
          idx_out[q * 3 + 1] = (int)(u32)k1;
          idx_out[q * 3 + 2] = (int)(u32)k2;
          w_out[q * 3 + 0] = w0 * inv;
          w_out[q * 3 + 1] = w1 * inv;
          w_out[q * 3 + 2] = w2 * inv;
        }
      } else if (sub == 0) {
        const u32 slot = atomicAdd(ovCnt, 1u);
        ovList[slot] = q;
      }
    }
  }
}

// ---------------------------------------------------------------- KNN fixup
// One wave per deferred query: lanes split the +-2 cell window (then the
// full cloud if still unresolved), 64-wide butterfly merge, lane 0 writes.
// Candidate sets and u64 keys identical to the old inline fallback.
__global__ __launch_bounds__(256) void fixup_kernel(
    const float4* __restrict__ pts4, const u32* __restrict__ cellCnt,
    const int* __restrict__ cellIdx, const float* __restrict__ pos_skip,
    const u32* __restrict__ ovCnt, const int* __restrict__ ovList,
    int* __restrict__ idx_out, float* __restrict__ w_out) {
#pragma clang fp contract(off)
  const int tid = threadIdx.x;
  const int lane = tid & 63;
  const int wv = tid >> 6;
  const int nOv = (int)*ovCnt;
  for (int i = blockIdx.x * 4 + wv; i < nOv; i += gridDim.x * 4) {
    const int q = ovList[i];
    const int b = q >> 14;
    const float qx = pos_skip[q * 3 + 0];
    const float qy = pos_skip[q * 3 + 1];
    const float qz = pos_skip[q * 3 + 2];
    const float q2 = (qx * qx + qy * qy) + qz * qz;
    int cx = (int)(qx * 8.0f); cx = cx < 0 ? 0 : (cx > 7 ? 7 : cx);
    int cy = (int)(qy * 8.0f); cy = cy < 0 ? 0 : (cy > 7 ? 7 : cy);
    int cz = (int)(qz * 8.0f); cz = cz < 0 ? 0 : (cz > 7 ? 7 : cz);
    const int ex0 = cx > 1 ? cx - 2 : 0, ex1 = cx < 6 ? cx + 2 : 7;
    const int ey0 = cy > 1 ? cy - 2 : 0, ey1 = cy < 6 ? cy + 2 : 7;
    const int ez0 = cz > 1 ? cz - 2 : 0, ez1 = cz < 6 ? cz + 2 : 7;
    const int nx = ex1 - ex0 + 1, ny = ey1 - ey0 + 1, nzc = ez1 - ez0 + 1;
    const int ncells = nx * ny * nzc;
    u64 k0 = ~0ull, k1 = ~0ull, k2 = ~0ull;
    for (int ci = lane; ci < ncells; ci += 64) {
      const int lz = ci / (nx * ny);
      const int rem = ci - lz * nx * ny;
      const int ly = rem / nx;
      const int lx = rem - ly * nx;
      const int cg = b * 512 + (ez0 + lz) * 64 + (ey0 + ly) * 8 + (ex0 + lx);
      u32 cnt = cellCnt[cg];
      if (cnt > CELL_CAP) cnt = CELL_CAP;
      const int cb = cg * CELL_CAP;
      for (u32 s = 0; s < cnt; ++s) {
        const int gi = cellIdx[cb + s];
        const float4 p = pts4[gi];
        const float dot = fmaf(qz, p.z, fmaf(qy, p.y, qx * p.x));
        const float tv = (q2 - 2.0f * dot) + p.w;
        ins3(((u64)flipf(tv) << 32) | (u32)gi, k0, k1, k2);
      }
    }
#pragma unroll
    for (int mask = 1; mask < 64; mask <<= 1) {
      const u64 r0 = shfl_xor_u64_w64(k0, mask);
      const u64 r1 = shfl_xor_u64_w64(k1, mask);
      const u64 r2 = shfl_xor_u64_w64(k2, mask);
      merge3(r0, r1, r2, k0, k1, k2);
    }
    float m2tv = unflipf((u32)(k2 >> 32));
    if (!(m2tv <= 0.0625f - 1e-5f)) {
      k0 = k1 = k2 = ~0ull;
      const int base = b * NPTS;
      for (int j = lane; j < NPTS; j += 64) {
        const int gi = base + j;
        const float4 p = pts4[gi];
        const float dot = fmaf(qz, p.z, fmaf(qy, p.y, qx * p.x));
        const float tv = (q2 - 2.0f * dot) + p.w;
        ins3(((u64)flipf(tv) << 32) | (u32)gi, k0, k1, k2);
      }
#pragma unroll
      for (int mask = 1; mask < 64; mask <<= 1) {
        const u64 r0 = shfl_xor_u64_w64(k0, mask);
        const u64 r1 = shfl_xor_u64_w64(k1, mask);
        const u64 r2 = shfl_xor_u64_w64(k2, mask);
        merge3(r0, r1, r2, k0, k1, k2);
      }
    }
    if (lane == 0) {
      const float t0 = unflipf((u32)(k0 >> 32));
      const float t1 = unflipf((u32)(k1 >> 32));
      const float t2 = unflipf((u32)(k2 >> 32));
      const float w0 = 1.0f / fmaxf(t0, 1e-16f);
      const float w1 = 1.0f / fmaxf(t1, 1e-16f);
      const float w2 = 1.0f / fmaxf(t2, 1e-16f);
      const float wsum = (w0 + w1) + w2;
      const float inv = 1.0f / wsum;
      idx_out[q * 3 + 0] = (int)(u32)k0;
      idx_out[q * 3 + 1] = (int)(u32)k1;
      idx_out[q * 3 + 2] = (int)(u32)k2;
      w_out[q * 3 + 0] = w0 * inv;
      w_out[q * 3 + 1] = w1 * inv;
      w_out[q * 3 + 2] = w2 * inv;
    }
  }
}

// ---------------------------------------------------------------- fused MLP
// Exact R3 configuration (measured best: 115.4 us, VGPR 80, 2 blocks/CU).
// LDS granule map: p(vg,row) = (vg&32) | ((vg&3)<<3) | (((vg>>2)&7) ^ (row&7))
// qPerm sorting: block's 64 rows come from ~2 cells -> their 3-NN gathers
// share ~40 unique x-rows -> L1/L2 hits instead of HBM.
__global__ __launch_bounds__(512, 2) void fused_mlp_kernel(
    const float* __restrict__ x, const int* __restrict__ idx,
    const float* __restrict__ w, const float* __restrict__ x_skip,
    const u16* __restrict__ W1s, const float* __restrict__ b1,
    const u16* __restrict__ W2s, const float* __restrict__ b2,
    const int* __restrict__ qPerm, float* __restrict__ out) {
  __shared__ __align__(16) u16 Abuf[64 * 512];   // 64 KB
  __shared__ int sPerm[64];
  const int tid = threadIdx.x;
  const int m0 = blockIdx.x * 64;

  if (tid < 64) sPerm[tid] = qPerm[m0 + tid];

  // ---- A-build: row = tid>>3 (64 rows), sub = tid&7
  {
    const int row = tid >> 3;
    const int sub = tid & 7;
    const int gr = qPerm[m0 + row];
    u16* rowp = Abuf + row * 512;
    const int rx = row & 7;
    if (sub < 4) {
      const int i0 = idx[gr * 3 + 0], i1 = idx[gr * 3 + 1], i2 = idx[gr * 3 + 2];
      const float w0 = w[gr * 3 + 0], w1 = w[gr * 3 + 1], w2 = w[gr * 3 + 2];
      const float4* p0 = (const float4*)(x + (size_t)i0 * CIN + sub * 64);
      const float4* p1 = (const float4*)(x + (size_t)i1 * CIN + sub * 64);
      const float4* p2 = (const float4*)(x + (size_t)i2 * CIN + sub * 64);
#pragma unroll
      for (int c = 0; c < 8; ++c) {
        const float4 a0 = p0[c * 2], a1 = p1[c * 2], a2 = p2[c * 2];
        const float4 d0 = p0[c * 2 + 1], d1 = p1[c * 2 + 1], d2 = p2[c * 2 + 1];
        u16 o[8];
        o[0] = f2bf(fmaf(w0, a0.x, fmaf(w1, a1.x, w2 * a2.x)));
        o[1] = f2bf(fmaf(w0, a0.y, fmaf(w1, a1.y, w2 * a2.y)));
        o[2] = f2bf(fmaf(w0, a0.z, fmaf(w1, a1.z, w2 * a2.z)));
        o[3] = f2bf(fmaf(w0, a0.w, fmaf(w1, a1.w, w2 * a2.w)));
        o[4] = f2bf(fmaf(w0, d0.x, fmaf(w1, d1.x, w2 * d2.x)));
        o[5] = f2bf(fmaf(w0, d0.y, fmaf(w1, d1.y, w2 * d2.y)));
        o[6] = f2bf(fmaf(w0, d0.z, fmaf(w1, d1.z, w2 * d2.z)));
        o[7] = f2bf(fmaf(w0, d0.w, fmaf(w1, d1.w, w2 * d2.w)));
        // vg = sub*8+c -> p = ((c&3)<<3) | ((2*sub + (c>>2)) ^ rx)
        const int pp = ((c & 3) << 3) | (((2 * sub + (c >> 2)) ^ rx) & 7);
        *(uint4*)(rowp + pp * 8) = *(const uint4*)o;
      }
    } else {
      const int ss = sub - 4;
      const float4* ps = (const float4*)(x_skip + (size_t)gr * CIN + ss * 64);
#pragma unroll
      for (int c = 0; c < 8; ++c) {
        const float4 a = ps[c * 2], d = ps[c * 2 + 1];
        u16 o[8];
        o[0] = f2bf(a.x); o[1] = f2bf(a.y); o[2] = f2bf(a.z); o[3] = f2bf(a.w);
        o[4] = f2bf(d.x); o[5] = f2bf(d.y); o[6] = f2bf(d.z); o[7] = f2bf(d.w);
        // vg = 32+ss*8+c -> p = 32 | ((c&3)<<3) | ((2*ss + (c>>2)) ^ rx)
        const int pp = 32 | ((c & 3) << 3) | (((2 * ss + (c >> 2)) ^ rx) & 7);
        *(uint4*)(rowp + pp * 8) = *(const uint4*)o;
      }
    }
  }
  __syncthreads();

  const int wid = tid >> 6;
  const int lane = tid & 63;
  const int fr = lane & 15;
  const int g = lane >> 4;
  const int frx = fr & 7;

  // ---- phase 1: H[64][512] = A[64][512] @ W1 (wave: m64 x n64)
  f32x4 acc[4][4];
#pragma unroll
  for (int mi = 0; mi < 4; mi++)
#pragma unroll
    for (int ni = 0; ni < 4; ni++) acc[mi][ni] = (f32x4){0.f, 0.f, 0.f, 0.f};

  {
    const u16* B1 = W1s + wid * 2048 + lane * 8;   // + kt*16384 + ni*512
    bf16x8 bf[2][4];
#pragma unroll
    for (int ni = 0; ni < 4; ni++)
      bf[0][ni] = *(const bf16x8*)(B1 + ni * 512);
    for (int kt = 0; kt < 16; ++kt) {
      const int cur = kt & 1;
      if (kt < 15) {
        const u16* nb = B1 + (kt + 1) * 16384;
#pragma unroll
        for (int ni = 0; ni < 4; ni++)
          bf[cur ^ 1][ni] = *(const bf16x8*)(nb + ni * 512);
      }
      bf16x8 af[4];
#pragma unroll
      for (int mi = 0; mi < 4; mi++)
        af[mi] = *(const bf16x8*)&Abuf[(mi * 16 + fr) * 512 +
            ((((kt >> 3) << 5) | (g << 3) | ((kt & 7) ^ frx)) * 8)];
#pragma unroll
      for (int mi = 0; mi < 4; mi++)
#pragma unroll
        for (int ni = 0; ni < 4; ni++)
          acc[mi][ni] = __builtin_amdgcn_mfma_f32_16x16x32_bf16(
              af[mi], bf[cur][ni], acc[mi][ni], 0, 0, 0);
    }
  }
  __syncthreads();                 // all Abuf reads complete

  // ---- relu + bias -> bf16 back into Abuf (as H, same swizzle map)
  {
    const int wn = wid * 64;
#pragma unroll
    for (int ni = 0; ni < 4; ni++) {
      const int n = wn + ni * 16 + fr;
      const float bb = b1[n];
      const int vg = n >> 3;
      const int nlow = n & 7;
      const int pb = (vg & 32) | ((vg & 3) << 3) | ((vg >> 2) & 7);
#pragma unroll
      for (int mi = 0; mi < 4; mi++) {
#pragma unroll
        for (int r = 0; r < 4; r++) {
          const int m = mi * 16 + g * 4 + r;
          const float v = fmaxf(acc[mi][ni][r] + bb, 0.f);
          Abuf[m * 512 + (pb ^ (m & 7)) * 8 + nlow] = f2bf(v);
        }
      }
    }
  }
  __syncthreads();                 // H complete

  // ---- phase 2: C[64][256] = H[64][512] @ W2 (wave: m64 x n32)
  f32x4 acc2[4][2];
#pragma unroll
  for (int mi = 0; mi < 4; mi++)
#pragma unroll
    for (int ni = 0; ni < 2; ni++) acc2[mi][ni] = (f32x4){0.f, 0.f, 0.f, 0.f};

  {
    const u16* B2 = W2s + wid * 1024 + lane * 8;   // + kt*8192 + ni*512
    bf16x8 bf[2][2];
#pragma unroll
    for (int ni = 0; ni < 2; ni++)
      bf[0][ni] = *(const bf16x8*)(B2 + ni * 512);
    for (int kt = 0; kt < 16; ++kt) {
      const int cur = kt & 1;
      if (kt < 15) {
        const u16* nb = B2 + (kt + 1) * 8192;
#pragma unroll
        for (int ni = 0; ni < 2; ni++)
          bf[cur ^ 1][ni] = *(const bf16x8*)(nb + ni * 512);
      }
      bf16x8 af[4];
#pragma unroll
      for (int mi = 0; mi < 4; mi++)
        af[mi] = *(const bf16x8*)&Abuf[(mi * 16 + fr) * 512 +
            ((((kt >> 3) << 5) | (g << 3) | ((kt & 7) ^ frx)) * 8)];
#pragma unroll
      for (int mi = 0; mi < 4; mi++)
#pragma unroll
        for (int ni = 0; ni < 2; ni++)
          acc2[mi][ni] = __builtin_amdgcn_mfma_f32_16x16x32_bf16(
              af[mi], bf[cur][ni], acc2[mi][ni], 0, 0, 0);
    }
  }

  // ---- epilogue: relu + bias2 -> f32 out (rows via sPerm)
#pragma unroll
  for (int ni = 0; ni < 2; ni++) {
    const int col = wid * 32 + ni * 16 + fr;
    const float bb = b2[col];
#pragma unroll
    for (int mi = 0; mi < 4; mi++) {
#pragma unroll
      for (int r = 0; r < 4; r++) {
        const int rowg = sPerm[mi * 16 + g * 4 + r];
        out[(size_t)rowg * CH2 + col] = fmaxf(acc2[mi][ni][r] + bb, 0.f);
      }
    }
  }
}

// ---------------------------------------------------------------- launch
extern "C" void kernel_launch(void* const* d_in, const int* in_sizes, int n_in,
                              void* d_out, int out_size, void* d_ws, size_t ws_size,
                              hipStream_t stream) {
  const float* x        = (const float*)d_in[0];
  const float* pos      = (const float*)d_in[1];
  const float* x_skip   = (const float*)d_in[3];
  const float* pos_skip = (const float*)d_in[4];
  const int*   batch_sk = (const int*)d_in[5];
  const float* W1       = (const float*)d_in[6];
  const float* b1       = (const float*)d_in[7];
  const float* W2       = (const float*)d_in[8];
  const float* b2       = (const float*)d_in[9];
  float* out = (float*)d_out;

  char* ws = (char*)d_ws;
  u16*    W1s     = (u16*)(ws);                 // 524288 B
  u16*    W2s     = (u16*)(ws + 524288);        // 262144 B
  int*    idxb    = (int*)(ws + 786432);        // 786432 B
  float*  wb      = (float*)(ws + 1572864);     // 786432 B
  float4* pts4    = (float4*)(ws + 2359296);    // 262144 B
  u32*    cellCnt = (u32*)(ws + 2621440);       // 8192 B
  u32*    qCnt    = (u32*)(ws + 2629632);       // 8192 B
  int*    cellIdx = (int*)(ws + 2637824);       // 327680 B
  int*    qIdx    = (int*)(ws + 2965504);       // 786432 B
  int*    qPerm   = (int*)(ws + 3751936);       // 262144 B
  u32*    ovCnt   = (u32*)(ws + 4014080);       // 4 B (+pad)
  int*    ovList  = (int*)(ws + 4014336);       // 262144 B
  // total 4,276,480 B

  hipMemsetAsync(cellCnt, 0, 16384, stream);    // cellCnt + qCnt
  hipMemsetAsync(ovCnt, 0, 4, stream);
  ptbin_kernel<<<dim3(1536), dim3(256), 0, stream>>>(
      W1, W2, W1s, W2s, pos_skip, batch_sk, out, pos, pts4,
      cellCnt, cellIdx, qCnt, qIdx);
  knn_kernel<<<dim3(2052), dim3(256), 0, stream>>>(pts4, cellCnt, cellIdx,
                                                   qCnt, qIdx, pos_skip,
                                                   idxb, wb, qPerm,
                                                   ovCnt, ovList);
  fixup_kernel<<<dim3(256), dim3(256), 0, stream>>>(pts4, cellCnt, cellIdx,
                                                    pos_skip, ovCnt, ovList,
                                                    idxb, wb);
  fused_mlp_kernel<<<dim3(1024), dim3(512), 0, stream>>>(
      x, idxb, wb, x_skip, W1s, b1, W2s, b2, qPerm, out);
}